// Round 2
// baseline (3171.074 us; speedup 1.0000x reference)
//
#include <hip/hip_runtime.h>
#include <math.h>

#define NN 50000
#define NE 800000
#define KDIM 256      // IN_F
#define CDIM 256      // NHEAD*OUT_F
#define NHEAD 4
#define HF 64         // OUT_F
#define ALPHA 0.2f

__device__ __forceinline__ void atomAddF(float* p, float v) {
#if defined(__HIP_DEVICE_COMPILE__)
  unsafeAtomicAdd(p, v);   // HW global_atomic_add_f32 on gfx950
#else
  atomicAdd(p, v);
#endif
}

// float atomic max via monotone int/uint reinterpretation (init must be -inf)
__device__ __forceinline__ void atomicMaxF(float* addr, float val) {
  if (val >= 0.0f) atomicMax((int*)addr, __float_as_int(val));
  else atomicMin((unsigned int*)addr, __float_as_uint(val));
}

__global__ __launch_bounds__(256) void fill_neginf(float* __restrict__ p, int n) {
  int i = blockIdx.x * 256 + threadIdx.x;
  if (i < n) p[i] = -INFINITY;
}

// H[M,256] = X[M,256] @ W[256,256]; fp32 vector GEMM, 64x64 tile, 4x4 microtile
__global__ __launch_bounds__(256) void gemm_xw(const float* __restrict__ X,
                                               const float* __restrict__ W,
                                               float* __restrict__ H, int M) {
  __shared__ float As[16][64];   // A stored transposed: As[k][row]
  __shared__ float Bs[16][64];   // Bs[k][col]
  const int tid = threadIdx.x;
  const int row0 = blockIdx.y * 64;
  const int col0 = blockIdx.x * 64;
  const int tx = tid & 15, ty = tid >> 4;
  const int arow = tid >> 2, akc = (tid & 3) * 4;
  const int brow = tid >> 4, bcol = (tid & 15) * 4;
  float acc[4][4] = {};
  for (int k0 = 0; k0 < KDIM; k0 += 16) {
    float4 a4 = make_float4(0.f, 0.f, 0.f, 0.f);
    int gr = row0 + arow;
    if (gr < M) a4 = *(const float4*)&X[(size_t)gr * KDIM + k0 + akc];
    As[akc + 0][arow] = a4.x;
    As[akc + 1][arow] = a4.y;
    As[akc + 2][arow] = a4.z;
    As[akc + 3][arow] = a4.w;
    *(float4*)&Bs[brow][bcol] = *(const float4*)&W[(size_t)(k0 + brow) * CDIM + col0 + bcol];
    __syncthreads();
#pragma unroll
    for (int kk = 0; kk < 16; ++kk) {
      float4 av = *(const float4*)&As[kk][ty * 4];
      float4 bv = *(const float4*)&Bs[kk][tx * 4];
      acc[0][0] += av.x * bv.x; acc[0][1] += av.x * bv.y; acc[0][2] += av.x * bv.z; acc[0][3] += av.x * bv.w;
      acc[1][0] += av.y * bv.x; acc[1][1] += av.y * bv.y; acc[1][2] += av.y * bv.z; acc[1][3] += av.y * bv.w;
      acc[2][0] += av.z * bv.x; acc[2][1] += av.z * bv.y; acc[2][2] += av.z * bv.z; acc[2][3] += av.z * bv.w;
      acc[3][0] += av.w * bv.x; acc[3][1] += av.w * bv.y; acc[3][2] += av.w * bv.z; acc[3][3] += av.w * bv.w;
    }
    __syncthreads();
  }
#pragma unroll
  for (int i = 0; i < 4; ++i) {
    int r = row0 + ty * 4 + i;
    if (r < M) {
      float4 v = make_float4(acc[i][0], acc[i][1], acc[i][2], acc[i][3]);
      *(float4*)&H[(size_t)r * CDIM + col0 + tx * 4] = v;
    }
  }
}

// per (node, head): hl = <h, a_l>, hr = <h, a_r>
__global__ __launch_bounds__(256) void attn_logits(const float* __restrict__ H,
                                                   const float* __restrict__ al,
                                                   const float* __restrict__ ar,
                                                   float* __restrict__ hl,
                                                   float* __restrict__ hr) {
  int idx = blockIdx.x * 256 + threadIdx.x;  // node*4 + head
  if (idx >= NN * NHEAD) return;
  int hd = idx & 3;
  const float* hp = H + (size_t)(idx >> 2) * CDIM + hd * HF;
  const float* alp = al + hd * HF;
  const float* arp = ar + hd * HF;
  float sl = 0.f, sr = 0.f;
#pragma unroll
  for (int f = 0; f < HF; f += 4) {
    float4 hv = *(const float4*)&hp[f];
    float4 av = *(const float4*)&alp[f];
    float4 bv = *(const float4*)&arp[f];
    sl += hv.x * av.x + hv.y * av.y + hv.z * av.z + hv.w * av.w;
    sr += hv.x * bv.x + hv.y * bv.y + hv.z * bv.z + hv.w * bv.w;
  }
  hl[idx] = sl;
  hr[idx] = sr;
}

// per edge: s = leaky_relu(hl[row] + hr[col]); store s; segment-max into emax[row]
__global__ __launch_bounds__(256) void edge_scores(const int* __restrict__ edge,
                                                   const float* __restrict__ hl,
                                                   const float* __restrict__ hr,
                                                   float* __restrict__ evals,
                                                   float* __restrict__ emax) {
  int e = blockIdx.x * 256 + threadIdx.x;
  if (e >= NE) return;
  int r = edge[e], c = edge[NE + e];
  float4 l = *(const float4*)&hl[(size_t)r * 4];
  float4 rr = *(const float4*)&hr[(size_t)c * 4];
  float4 s;
  s.x = l.x + rr.x; s.x = s.x > 0.f ? s.x : ALPHA * s.x;
  s.y = l.y + rr.y; s.y = s.y > 0.f ? s.y : ALPHA * s.y;
  s.z = l.z + rr.z; s.z = s.z > 0.f ? s.z : ALPHA * s.z;
  s.w = l.w + rr.w; s.w = s.w > 0.f ? s.w : ALPHA * s.w;
  *(float4*)&evals[(size_t)e * 4] = s;
  atomicMaxF(&emax[r * 4 + 0], s.x);
  atomicMaxF(&emax[r * 4 + 1], s.y);
  atomicMaxF(&emax[r * 4 + 2], s.z);
  atomicMaxF(&emax[r * 4 + 3], s.w);
}

// per edge: ee = exp(s - emax[row]); store ee; segment-sum into denom[row]
__global__ __launch_bounds__(256) void edge_exp(const int* __restrict__ edge,
                                                float* __restrict__ evals,
                                                const float* __restrict__ emax,
                                                float* __restrict__ denom) {
  int e = blockIdx.x * 256 + threadIdx.x;
  if (e >= NE) return;
  int r = edge[e];
  float4 s = *(const float4*)&evals[(size_t)e * 4];
  float4 m = *(const float4*)&emax[(size_t)r * 4];
  float4 ee;
  ee.x = __expf(s.x - m.x);
  ee.y = __expf(s.y - m.y);
  ee.z = __expf(s.z - m.z);
  ee.w = __expf(s.w - m.w);
  *(float4*)&evals[(size_t)e * 4] = ee;
  atomAddF(&denom[r * 4 + 0], ee.x);
  atomAddF(&denom[r * 4 + 1], ee.y);
  atomAddF(&denom[r * 4 + 2], ee.z);
  atomAddF(&denom[r * 4 + 3], ee.w);
}

// one wave per edge: out[row] += (ee/denom[row]) * h[col]  (256 floats, 4/lane)
__global__ __launch_bounds__(256) void aggregate(const int* __restrict__ edge,
                                                 const float* __restrict__ evals,
                                                 const float* __restrict__ denom,
                                                 const float* __restrict__ H,
                                                 float* __restrict__ out) {
  int wid = (int)((blockIdx.x * 256 + threadIdx.x) >> 6);
  int lane = threadIdx.x & 63;
  if (wid >= NE) return;
  int r = edge[wid], c = edge[NE + wid];
  float4 ee = *(const float4*)&evals[(size_t)wid * 4];
  float4 dn = *(const float4*)&denom[(size_t)r * 4];
  float a0 = ee.x / dn.x, a1 = ee.y / dn.y, a2 = ee.z / dn.z, a3 = ee.w / dn.w;
  int hd = lane >> 4;
  float a = hd == 0 ? a0 : (hd == 1 ? a1 : (hd == 2 ? a2 : a3));
  int f = lane * 4;
  float4 hv = *(const float4*)&H[(size_t)c * CDIM + f];
  float* op = out + (size_t)r * CDIM + f;
  atomAddF(op + 0, a * hv.x);
  atomAddF(op + 1, a * hv.y);
  atomAddF(op + 2, a * hv.z);
  atomAddF(op + 3, a * hv.w);
}

extern "C" void kernel_launch(void* const* d_in, const int* in_sizes, int n_in,
                              void* d_out, int out_size, void* d_ws, size_t ws_size,
                              hipStream_t stream) {
  const float* x   = (const float*)d_in[0];
  const int*  edge = (const int*)d_in[1];
  const float* W   = (const float*)d_in[2];
  const float* al  = (const float*)d_in[3];
  const float* ar  = (const float*)d_in[4];
  float* out = (float*)d_out;

  float* ws = (float*)d_ws;
  float* h     = ws;                          // NN*256 = 12,800,000
  float* hl    = h + (size_t)NN * CDIM;       // NN*4
  float* hr    = hl + (size_t)NN * NHEAD;     // NN*4
  float* emax  = hr + (size_t)NN * NHEAD;     // NN*4
  float* denom = emax + (size_t)NN * NHEAD;   // NN*4
  float* evals = denom + (size_t)NN * NHEAD;  // NE*4 = 3,200,000

  hipMemsetAsync(out, 0, (size_t)out_size * sizeof(float), stream);
  hipMemsetAsync(denom, 0, (size_t)NN * NHEAD * sizeof(float), stream);
  fill_neginf<<<(NN * NHEAD + 255) / 256, 256, 0, stream>>>(emax, NN * NHEAD);

  gemm_xw<<<dim3(CDIM / 64, (NN + 63) / 64), 256, 0, stream>>>(x, W, h, NN);
  attn_logits<<<(NN * NHEAD + 255) / 256, 256, 0, stream>>>(h, al, ar, hl, hr);
  edge_scores<<<(NE + 255) / 256, 256, 0, stream>>>(edge, hl, hr, evals, emax);
  edge_exp<<<(NE + 255) / 256, 256, 0, stream>>>(edge, evals, emax, denom);
  aggregate<<<NE / 4, 256, 0, stream>>>(edge, evals, denom, h, out);
}

// Round 3
// 462.923 us; speedup vs baseline: 6.8501x; 6.8501x over previous
//
#include <hip/hip_runtime.h>
#include <math.h>

#define NN 50000
#define NE 800000
#define KDIM 256      // IN_F
#define CDIM 256      // NHEAD*OUT_F
#define NHEAD 4
#define HF 64         // OUT_F
#define ALPHA 0.2f
#define SCAN_NBLK ((NN + 1023) / 1024)   // 49

// ---------------- CSR build ----------------

__global__ __launch_bounds__(256) void deg_count(const int* __restrict__ edge,
                                                 int* __restrict__ deg) {
  int e = blockIdx.x * 256 + threadIdx.x;
  if (e < NE) atomicAdd(&deg[edge[e]], 1);
}

// block-level exclusive scan: 1024 elements/block, write per-block totals
__global__ __launch_bounds__(256) void scan_blocks(const int* __restrict__ deg,
                                                   int* __restrict__ rowptr,
                                                   int* __restrict__ partials) {
  __shared__ int sc[256];
  int t = threadIdx.x;
  int base = blockIdx.x * 1024 + t * 4;
  int v[4];
#pragma unroll
  for (int i = 0; i < 4; ++i) v[i] = (base + i < NN) ? deg[base + i] : 0;
  int tsum = v[0] + v[1] + v[2] + v[3];
  sc[t] = tsum;
  __syncthreads();
  for (int off = 1; off < 256; off <<= 1) {
    int x = sc[t];
    int y = (t >= off) ? sc[t - off] : 0;
    __syncthreads();
    sc[t] = x + y;
    __syncthreads();
  }
  if (t == 255) partials[blockIdx.x] = sc[255];
  int run = (t > 0) ? sc[t - 1] : 0;
#pragma unroll
  for (int i = 0; i < 4; ++i) {
    if (base + i < NN) rowptr[base + i] = run;
    run += v[i];
  }
}

__global__ void scan_partials(int* __restrict__ partials) {
  if (threadIdx.x == 0) {
    int run = 0;
    for (int i = 0; i < SCAN_NBLK; ++i) { int v = partials[i]; partials[i] = run; run += v; }
  }
}

__global__ __launch_bounds__(256) void scan_add(int* __restrict__ rowptr,
                                                const int* __restrict__ partials) {
  int i = blockIdx.x * 256 + threadIdx.x;
  if (i < NN) rowptr[i] += partials[i >> 10];
  if (i == 0) rowptr[NN] = NE;
}

// scatter edges into row-sorted order; compute leaky-relu scores inline
__global__ __launch_bounds__(256) void scatter_edges(const int* __restrict__ edge,
                                                     const int* __restrict__ rowptr,
                                                     int* __restrict__ fill,
                                                     const float* __restrict__ hl,
                                                     const float* __restrict__ hr,
                                                     int* __restrict__ colsorted,
                                                     float4* __restrict__ s4) {
  int e = blockIdx.x * 256 + threadIdx.x;
  if (e >= NE) return;
  int r = edge[e], c = edge[NE + e];
  int pos = rowptr[r] + atomicAdd(&fill[r], 1);
  colsorted[pos] = c;
  float4 l = *(const float4*)&hl[(size_t)r * 4];
  float4 rr = *(const float4*)&hr[(size_t)c * 4];
  float4 s;
  s.x = l.x + rr.x; s.x = s.x > 0.f ? s.x : ALPHA * s.x;
  s.y = l.y + rr.y; s.y = s.y > 0.f ? s.y : ALPHA * s.y;
  s.z = l.z + rr.z; s.z = s.z > 0.f ? s.z : ALPHA * s.z;
  s.w = l.w + rr.w; s.w = s.w > 0.f ? s.w : ALPHA * s.w;
  s4[pos] = s;
}

// ---------------- projection GEMM ----------------

__global__ __launch_bounds__(256) void gemm_xw(const float* __restrict__ X,
                                               const float* __restrict__ W,
                                               float* __restrict__ H, int M) {
  __shared__ float As[16][64];
  __shared__ float Bs[16][64];
  const int tid = threadIdx.x;
  const int row0 = blockIdx.y * 64;
  const int col0 = blockIdx.x * 64;
  const int tx = tid & 15, ty = tid >> 4;
  const int arow = tid >> 2, akc = (tid & 3) * 4;
  const int brow = tid >> 4, bcol = (tid & 15) * 4;
  float acc[4][4] = {};
  for (int k0 = 0; k0 < KDIM; k0 += 16) {
    float4 a4 = make_float4(0.f, 0.f, 0.f, 0.f);
    int gr = row0 + arow;
    if (gr < M) a4 = *(const float4*)&X[(size_t)gr * KDIM + k0 + akc];
    As[akc + 0][arow] = a4.x;
    As[akc + 1][arow] = a4.y;
    As[akc + 2][arow] = a4.z;
    As[akc + 3][arow] = a4.w;
    *(float4*)&Bs[brow][bcol] = *(const float4*)&W[(size_t)(k0 + brow) * CDIM + col0 + bcol];
    __syncthreads();
#pragma unroll
    for (int kk = 0; kk < 16; ++kk) {
      float4 av = *(const float4*)&As[kk][ty * 4];
      float4 bv = *(const float4*)&Bs[kk][tx * 4];
      acc[0][0] += av.x * bv.x; acc[0][1] += av.x * bv.y; acc[0][2] += av.x * bv.z; acc[0][3] += av.x * bv.w;
      acc[1][0] += av.y * bv.x; acc[1][1] += av.y * bv.y; acc[1][2] += av.y * bv.z; acc[1][3] += av.y * bv.w;
      acc[2][0] += av.z * bv.x; acc[2][1] += av.z * bv.y; acc[2][2] += av.z * bv.z; acc[2][3] += av.z * bv.w;
      acc[3][0] += av.w * bv.x; acc[3][1] += av.w * bv.y; acc[3][2] += av.w * bv.z; acc[3][3] += av.w * bv.w;
    }
    __syncthreads();
  }
#pragma unroll
  for (int i = 0; i < 4; ++i) {
    int r = row0 + ty * 4 + i;
    if (r < M) {
      float4 v = make_float4(acc[i][0], acc[i][1], acc[i][2], acc[i][3]);
      *(float4*)&H[(size_t)r * CDIM + col0 + tx * 4] = v;
    }
  }
}

// per (node, head): hl = <h, a_l>, hr = <h, a_r>
__global__ __launch_bounds__(256) void attn_logits(const float* __restrict__ H,
                                                   const float* __restrict__ al,
                                                   const float* __restrict__ ar,
                                                   float* __restrict__ hl,
                                                   float* __restrict__ hr) {
  int idx = blockIdx.x * 256 + threadIdx.x;  // node*4 + head
  if (idx >= NN * NHEAD) return;
  int hd = idx & 3;
  const float* hp = H + (size_t)(idx >> 2) * CDIM + hd * HF;
  const float* alp = al + hd * HF;
  const float* arp = ar + hd * HF;
  float sl = 0.f, sr = 0.f;
#pragma unroll
  for (int f = 0; f < HF; f += 4) {
    float4 hv = *(const float4*)&hp[f];
    float4 av = *(const float4*)&alp[f];
    float4 bv = *(const float4*)&arp[f];
    sl += hv.x * av.x + hv.y * av.y + hv.z * av.z + hv.w * av.w;
    sr += hv.x * bv.x + hv.y * bv.y + hv.z * bv.z + hv.w * bv.w;
  }
  hl[idx] = sl;
  hr[idx] = sr;
}

// ---------------- per-row softmax (wave per row, no atomics) ----------------

__global__ __launch_bounds__(256) void row_softmax(const int* __restrict__ rowptr,
                                                   float4* __restrict__ s4,
                                                   float4* __restrict__ rdenom) {
  int wid = (int)((blockIdx.x * 256 + threadIdx.x) >> 6);
  int lane = threadIdx.x & 63;
  if (wid >= NN) return;
  int s = rowptr[wid], e = rowptr[wid + 1];
  int d = e - s;
  float4 mx = make_float4(-INFINITY, -INFINITY, -INFINITY, -INFINITY);
  for (int i = lane; i < d; i += 64) {
    float4 v = s4[s + i];
    mx.x = fmaxf(mx.x, v.x); mx.y = fmaxf(mx.y, v.y);
    mx.z = fmaxf(mx.z, v.z); mx.w = fmaxf(mx.w, v.w);
  }
#pragma unroll
  for (int off = 1; off < 64; off <<= 1) {
    mx.x = fmaxf(mx.x, __shfl_xor(mx.x, off));
    mx.y = fmaxf(mx.y, __shfl_xor(mx.y, off));
    mx.z = fmaxf(mx.z, __shfl_xor(mx.z, off));
    mx.w = fmaxf(mx.w, __shfl_xor(mx.w, off));
  }
  float4 sum = make_float4(0.f, 0.f, 0.f, 0.f);
  for (int i = lane; i < d; i += 64) {
    float4 v = s4[s + i];
    float4 ee;
    ee.x = __expf(v.x - mx.x);
    ee.y = __expf(v.y - mx.y);
    ee.z = __expf(v.z - mx.z);
    ee.w = __expf(v.w - mx.w);
    s4[s + i] = ee;
    sum.x += ee.x; sum.y += ee.y; sum.z += ee.z; sum.w += ee.w;
  }
#pragma unroll
  for (int off = 1; off < 64; off <<= 1) {
    sum.x += __shfl_xor(sum.x, off);
    sum.y += __shfl_xor(sum.y, off);
    sum.z += __shfl_xor(sum.z, off);
    sum.w += __shfl_xor(sum.w, off);
  }
  if (lane == 0) {
    float4 rd;
    rd.x = sum.x > 0.f ? 1.f / sum.x : 0.f;
    rd.y = sum.y > 0.f ? 1.f / sum.y : 0.f;
    rd.z = sum.z > 0.f ? 1.f / sum.z : 0.f;
    rd.w = sum.w > 0.f ? 1.f / sum.w : 0.f;
    rdenom[wid] = rd;
  }
}

// ---------------- per-row aggregation (wave per row, atomic-free) ----------------

__global__ __launch_bounds__(256) void row_aggregate(const int* __restrict__ rowptr,
                                                     const int* __restrict__ colsorted,
                                                     const float4* __restrict__ s4,
                                                     const float4* __restrict__ rdenom,
                                                     const float* __restrict__ H,
                                                     float* __restrict__ out) {
  int wid = (int)((blockIdx.x * 256 + threadIdx.x) >> 6);
  int lane = threadIdx.x & 63;
  if (wid >= NN) return;
  int s = rowptr[wid], e = rowptr[wid + 1];
  int head = lane >> 4;
  float4 rd4 = rdenom[wid];
  float rd = head == 0 ? rd4.x : (head == 1 ? rd4.y : (head == 2 ? rd4.z : rd4.w));
  float4 acc = make_float4(0.f, 0.f, 0.f, 0.f);
  int f = lane * 4;
  for (int i = s; i < e; ++i) {
    int c = colsorted[i];                 // wave-uniform broadcast load
    float4 ee = s4[i];                    // wave-uniform broadcast load
    float a = (head == 0 ? ee.x : (head == 1 ? ee.y : (head == 2 ? ee.z : ee.w))) * rd;
    float4 hv = *(const float4*)&H[(size_t)c * CDIM + f];
    acc.x += a * hv.x; acc.y += a * hv.y; acc.z += a * hv.z; acc.w += a * hv.w;
  }
  *(float4*)&out[(size_t)wid * CDIM + f] = acc;
}

// ---------------- launch ----------------

extern "C" void kernel_launch(void* const* d_in, const int* in_sizes, int n_in,
                              void* d_out, int out_size, void* d_ws, size_t ws_size,
                              hipStream_t stream) {
  const float* x   = (const float*)d_in[0];
  const int*  edge = (const int*)d_in[1];
  const float* W   = (const float*)d_in[2];
  const float* al  = (const float*)d_in[3];
  const float* ar  = (const float*)d_in[4];
  float* out = (float*)d_out;

  float* ws = (float*)d_ws;
  float* h        = ws;                              // NN*256
  float* hl       = h + (size_t)NN * CDIM;           // NN*4
  float* hr       = hl + (size_t)NN * NHEAD;         // NN*4
  float* rdenom   = hr + (size_t)NN * NHEAD;         // NN*4 (float4/node)
  float* s4sorted = rdenom + (size_t)NN * NHEAD;     // NE*4
  int* deg       = (int*)(s4sorted + (size_t)NE * 4);  // NN
  int* fill      = deg + NN;                           // NN
  int* rowptr    = fill + NN;                          // NN+1
  int* partials  = rowptr + NN + 1;                    // 64
  int* colsorted = partials + 64;                      // NE

  // zero deg + fill in one shot (contiguous)
  hipMemsetAsync(deg, 0, (size_t)2 * NN * sizeof(int), stream);

  deg_count<<<(NE + 255) / 256, 256, 0, stream>>>(edge, deg);
  scan_blocks<<<SCAN_NBLK, 256, 0, stream>>>(deg, rowptr, partials);
  scan_partials<<<1, 64, 0, stream>>>(partials);
  scan_add<<<(NN + 255) / 256, 256, 0, stream>>>(rowptr, partials);

  gemm_xw<<<dim3(CDIM / 64, (NN + 63) / 64), 256, 0, stream>>>(x, W, h, NN);
  attn_logits<<<(NN * NHEAD + 255) / 256, 256, 0, stream>>>(h, al, ar, hl, hr);

  scatter_edges<<<(NE + 255) / 256, 256, 0, stream>>>(edge, rowptr, fill, hl, hr,
                                                      colsorted, (float4*)s4sorted);
  row_softmax<<<(NN * 64 + 255) / 256, 256, 0, stream>>>(rowptr, (float4*)s4sorted,
                                                         (float4*)rdenom);
  row_aggregate<<<(NN * 64 + 255) / 256, 256, 0, stream>>>(rowptr, colsorted,
                                                           (const float4*)s4sorted,
                                                           (const float4*)rdenom, h, out);
}

// Round 4
// 393.457 us; speedup vs baseline: 8.0595x; 1.1766x over previous
//
#include <hip/hip_runtime.h>
#include <math.h>

#define NN 50000
#define NE 800000
#define KDIM 256      // IN_F
#define CDIM 256      // NHEAD*OUT_F
#define NHEAD 4
#define HF 64         // OUT_F
#define ALPHA 0.2f
#define SCAN_NBLK ((NN + 1023) / 1024)   // 49

// ---------------- helpers ----------------

__device__ __forceinline__ unsigned short f2bf(float f) {  // RNE bf16
  unsigned u = __float_as_uint(f);
  return (unsigned short)((u + 0x7FFFu + ((u >> 16) & 1u)) >> 16);
}
__device__ __forceinline__ float4 bf4_to_f4(ushort4 u) {
  float4 r;
  r.x = __uint_as_float((unsigned)u.x << 16);
  r.y = __uint_as_float((unsigned)u.y << 16);
  r.z = __uint_as_float((unsigned)u.z << 16);
  r.w = __uint_as_float((unsigned)u.w << 16);
  return r;
}

// ---------------- CSR build ----------------

__global__ __launch_bounds__(256) void deg_count(const int* __restrict__ edge,
                                                 int* __restrict__ deg) {
  int e = blockIdx.x * 256 + threadIdx.x;
  if (e < NE) atomicAdd(&deg[edge[e]], 1);
}

__global__ __launch_bounds__(256) void scan_blocks(const int* __restrict__ deg,
                                                   int* __restrict__ rowptr,
                                                   int* __restrict__ partials) {
  __shared__ int sc[256];
  int t = threadIdx.x;
  int base = blockIdx.x * 1024 + t * 4;
  int v[4];
#pragma unroll
  for (int i = 0; i < 4; ++i) v[i] = (base + i < NN) ? deg[base + i] : 0;
  int tsum = v[0] + v[1] + v[2] + v[3];
  sc[t] = tsum;
  __syncthreads();
  for (int off = 1; off < 256; off <<= 1) {
    int x = sc[t];
    int y = (t >= off) ? sc[t - off] : 0;
    __syncthreads();
    sc[t] = x + y;
    __syncthreads();
  }
  if (t == 255) partials[blockIdx.x] = sc[255];
  int run = (t > 0) ? sc[t - 1] : 0;
#pragma unroll
  for (int i = 0; i < 4; ++i) {
    if (base + i < NN) rowptr[base + i] = run;
    run += v[i];
  }
}

__global__ void scan_partials(int* __restrict__ partials) {
  if (threadIdx.x == 0) {
    int run = 0;
    for (int i = 0; i < SCAN_NBLK; ++i) { int v = partials[i]; partials[i] = run; run += v; }
  }
}

__global__ __launch_bounds__(256) void scan_add(int* __restrict__ rowptr,
                                                const int* __restrict__ partials) {
  int i = blockIdx.x * 256 + threadIdx.x;
  if (i < NN) rowptr[i] += partials[i >> 10];
  if (i == 0) rowptr[NN] = NE;
}

// scatter edges into row-sorted order (cols only)
__global__ __launch_bounds__(256) void scatter_edges(const int* __restrict__ edge,
                                                     const int* __restrict__ rowptr,
                                                     int* __restrict__ fill,
                                                     int* __restrict__ colsorted) {
  int e = blockIdx.x * 256 + threadIdx.x;
  if (e >= NE) return;
  int r = edge[e], c = edge[NE + e];
  int pos = rowptr[r] + atomicAdd(&fill[r], 1);
  colsorted[pos] = c;
}

// ---------------- projection GEMM (fp32 vector) ----------------

__global__ __launch_bounds__(256) void gemm_xw(const float* __restrict__ X,
                                               const float* __restrict__ W,
                                               float* __restrict__ H, int M) {
  __shared__ float As[16][64];
  __shared__ float Bs[16][64];
  const int tid = threadIdx.x;
  const int row0 = blockIdx.y * 64;
  const int col0 = blockIdx.x * 64;
  const int tx = tid & 15, ty = tid >> 4;
  const int arow = tid >> 2, akc = (tid & 3) * 4;
  const int brow = tid >> 4, bcol = (tid & 15) * 4;
  float acc[4][4] = {};
  for (int k0 = 0; k0 < KDIM; k0 += 16) {
    float4 a4 = make_float4(0.f, 0.f, 0.f, 0.f);
    int gr = row0 + arow;
    if (gr < M) a4 = *(const float4*)&X[(size_t)gr * KDIM + k0 + akc];
    As[akc + 0][arow] = a4.x;
    As[akc + 1][arow] = a4.y;
    As[akc + 2][arow] = a4.z;
    As[akc + 3][arow] = a4.w;
    *(float4*)&Bs[brow][bcol] = *(const float4*)&W[(size_t)(k0 + brow) * CDIM + col0 + bcol];
    __syncthreads();
#pragma unroll
    for (int kk = 0; kk < 16; ++kk) {
      float4 av = *(const float4*)&As[kk][ty * 4];
      float4 bv = *(const float4*)&Bs[kk][tx * 4];
      acc[0][0] += av.x * bv.x; acc[0][1] += av.x * bv.y; acc[0][2] += av.x * bv.z; acc[0][3] += av.x * bv.w;
      acc[1][0] += av.y * bv.x; acc[1][1] += av.y * bv.y; acc[1][2] += av.y * bv.z; acc[1][3] += av.y * bv.w;
      acc[2][0] += av.z * bv.x; acc[2][1] += av.z * bv.y; acc[2][2] += av.z * bv.z; acc[2][3] += av.z * bv.w;
      acc[3][0] += av.w * bv.x; acc[3][1] += av.w * bv.y; acc[3][2] += av.w * bv.z; acc[3][3] += av.w * bv.w;
    }
    __syncthreads();
  }
#pragma unroll
  for (int i = 0; i < 4; ++i) {
    int r = row0 + ty * 4 + i;
    if (r < M) {
      float4 v = make_float4(acc[i][0], acc[i][1], acc[i][2], acc[i][3]);
      *(float4*)&H[(size_t)r * CDIM + col0 + tx * 4] = v;
    }
  }
}

// per (node, head): hl/hr dots; also emit bf16 copy of h for the gather
__global__ __launch_bounds__(256) void attn_logits_bf16(const float* __restrict__ H,
                                                        const float* __restrict__ al,
                                                        const float* __restrict__ ar,
                                                        float* __restrict__ hl,
                                                        float* __restrict__ hr,
                                                        unsigned short* __restrict__ hb) {
  int idx = blockIdx.x * 256 + threadIdx.x;  // node*4 + head
  if (idx >= NN * NHEAD) return;
  int hd = idx & 3;
  const float* hp = H + (size_t)(idx >> 2) * CDIM + hd * HF;
  unsigned short* hbp = hb + (size_t)(idx >> 2) * CDIM + hd * HF;
  const float* alp = al + hd * HF;
  const float* arp = ar + hd * HF;
  float sl = 0.f, sr = 0.f;
#pragma unroll
  for (int f = 0; f < HF; f += 4) {
    float4 hv = *(const float4*)&hp[f];
    float4 av = *(const float4*)&alp[f];
    float4 bv = *(const float4*)&arp[f];
    sl += hv.x * av.x + hv.y * av.y + hv.z * av.z + hv.w * av.w;
    sr += hv.x * bv.x + hv.y * bv.y + hv.z * bv.z + hv.w * bv.w;
    ushort4 u;
    u.x = f2bf(hv.x); u.y = f2bf(hv.y); u.z = f2bf(hv.z); u.w = f2bf(hv.w);
    *(ushort4*)&hbp[f] = u;
  }
  hl[idx] = sl;
  hr[idx] = sr;
}

// ---------------- fused per-row softmax+aggregate (wave per row) ----------------
// out[row] = sum_e exp(leaky(hl[row]+hr[col])) * h[col] / sum_e exp(...)
// (softmax is shift-invariant; scores bounded ~|12| so no max-subtract needed)
__global__ __launch_bounds__(256) void row_aggregate(const int* __restrict__ rowptr,
                                                     const int* __restrict__ colsorted,
                                                     const float* __restrict__ hl,
                                                     const float* __restrict__ hr,
                                                     const unsigned short* __restrict__ hb,
                                                     float* __restrict__ out) {
  int wid = (int)((blockIdx.x * 256 + threadIdx.x) >> 6);
  int lane = threadIdx.x & 63;
  if (wid >= NN) return;
  int s = rowptr[wid], e = rowptr[wid + 1];
  int head = lane >> 4;
  float hlv = hl[(size_t)wid * 4 + head];
  float4 acc = make_float4(0.f, 0.f, 0.f, 0.f);
  float den = 0.f;
  for (int i = s; i < e; ++i) {
    int c = colsorted[i];                             // wave-uniform broadcast
    float sc = hlv + hr[(size_t)c * 4 + head];
    sc = sc > 0.f ? sc : ALPHA * sc;
    float ee = __expf(sc);
    den += ee;
    ushort4 u = *(const ushort4*)&hb[(size_t)c * CDIM + lane * 4];
    float4 hv = bf4_to_f4(u);
    acc.x += ee * hv.x; acc.y += ee * hv.y; acc.z += ee * hv.z; acc.w += ee * hv.w;
  }
  float rd = den > 0.f ? 1.f / den : 0.f;
  acc.x *= rd; acc.y *= rd; acc.z *= rd; acc.w *= rd;
  *(float4*)&out[(size_t)wid * CDIM + lane * 4] = acc;
}

// ---------------- launch ----------------

extern "C" void kernel_launch(void* const* d_in, const int* in_sizes, int n_in,
                              void* d_out, int out_size, void* d_ws, size_t ws_size,
                              hipStream_t stream) {
  const float* x   = (const float*)d_in[0];
  const int*  edge = (const int*)d_in[1];
  const float* W   = (const float*)d_in[2];
  const float* al  = (const float*)d_in[3];
  const float* ar  = (const float*)d_in[4];
  float* out = (float*)d_out;

  float* ws = (float*)d_ws;
  float* h  = ws;                                   // NN*256 fp32
  float* hl = h + (size_t)NN * CDIM;                // NN*4
  float* hr = hl + (size_t)NN * NHEAD;              // NN*4
  unsigned short* hb = (unsigned short*)(hr + (size_t)NN * NHEAD);  // NN*256 bf16
  int* deg       = (int*)(hb + (size_t)NN * CDIM);  // NN
  int* fill      = deg + NN;                        // NN
  int* rowptr    = fill + NN;                       // NN+1
  int* partials  = rowptr + NN + 1;                 // 64
  int* colsorted = partials + 64;                   // NE

  hipMemsetAsync(deg, 0, (size_t)2 * NN * sizeof(int), stream);  // deg + fill

  deg_count<<<(NE + 255) / 256, 256, 0, stream>>>(edge, deg);
  scan_blocks<<<SCAN_NBLK, 256, 0, stream>>>(deg, rowptr, partials);
  scan_partials<<<1, 64, 0, stream>>>(partials);
  scan_add<<<(NN + 255) / 256, 256, 0, stream>>>(rowptr, partials);
  scatter_edges<<<(NE + 255) / 256, 256, 0, stream>>>(edge, rowptr, fill, colsorted);

  gemm_xw<<<dim3(CDIM / 64, (NN + 63) / 64), 256, 0, stream>>>(x, W, h, NN);
  attn_logits_bf16<<<(NN * NHEAD + 255) / 256, 256, 0, stream>>>(h, al, ar, hl, hr, hb);

  row_aggregate<<<(NN * 64 + 255) / 256, 256, 0, stream>>>(rowptr, colsorted, hl, hr, hb, out);
}

// Round 6
// 372.890 us; speedup vs baseline: 8.5040x; 1.0552x over previous
//
#include <hip/hip_runtime.h>
#include <math.h>

#define NN 50000
#define NE 800000
#define KDIM 256      // IN_F
#define CDIM 256      // NHEAD*OUT_F
#define NHEAD 4
#define HF 64         // OUT_F
#define ALPHA 0.2f
#define SCAN_NBLK ((NN + 1023) / 1024)   // 49

typedef short bh8 __attribute__((ext_vector_type(8)));   // 8 bf16 (4 VGPR)
typedef float f32x4 __attribute__((ext_vector_type(4)));

// ---------------- helpers ----------------

__device__ __forceinline__ unsigned short f2bf(float f) {  // RNE bf16
  unsigned u = __float_as_uint(f);
  return (unsigned short)((u + 0x7FFFu + ((u >> 16) & 1u)) >> 16);
}
__device__ __forceinline__ float bf2f(unsigned short u) {
  return __uint_as_float((unsigned)u << 16);
}
__device__ __forceinline__ float4 bf4_to_f4(ushort4 u) {
  float4 r;
  r.x = bf2f(u.x); r.y = bf2f(u.y); r.z = bf2f(u.z); r.w = bf2f(u.w);
  return r;
}

// ---------------- CSR build ----------------

__global__ __launch_bounds__(256) void deg_count(const int* __restrict__ edge,
                                                 int* __restrict__ deg) {
  int e = blockIdx.x * 256 + threadIdx.x;
  if (e < NE) atomicAdd(&deg[edge[e]], 1);
}

__global__ __launch_bounds__(256) void scan_blocks(const int* __restrict__ deg,
                                                   int* __restrict__ rowptr,
                                                   int* __restrict__ partials) {
  __shared__ int sc[256];
  int t = threadIdx.x;
  int base = blockIdx.x * 1024 + t * 4;
  int v[4];
#pragma unroll
  for (int i = 0; i < 4; ++i) v[i] = (base + i < NN) ? deg[base + i] : 0;
  int tsum = v[0] + v[1] + v[2] + v[3];
  sc[t] = tsum;
  __syncthreads();
  for (int off = 1; off < 256; off <<= 1) {
    int x = sc[t];
    int y = (t >= off) ? sc[t - off] : 0;
    __syncthreads();
    sc[t] = x + y;
    __syncthreads();
  }
  if (t == 255) partials[blockIdx.x] = sc[255];
  int run = (t > 0) ? sc[t - 1] : 0;
#pragma unroll
  for (int i = 0; i < 4; ++i) {
    if (base + i < NN) rowptr[base + i] = run;
    run += v[i];
  }
}

__global__ void scan_partials(int* __restrict__ partials) {
  if (threadIdx.x == 0) {
    int run = 0;
    for (int i = 0; i < SCAN_NBLK; ++i) { int v = partials[i]; partials[i] = run; run += v; }
  }
}

__global__ __launch_bounds__(256) void scan_add(int* __restrict__ rowptr,
                                                const int* __restrict__ partials) {
  int i = blockIdx.x * 256 + threadIdx.x;
  if (i < NN) rowptr[i] += partials[i >> 10];
  if (i == 0) rowptr[NN] = NE;
}

__global__ __launch_bounds__(256) void scatter_edges(const int* __restrict__ edge,
                                                     const int* __restrict__ rowptr,
                                                     int* __restrict__ fill,
                                                     int* __restrict__ colsorted) {
  int e = blockIdx.x * 256 + threadIdx.x;
  if (e >= NE) return;
  int r = edge[e], c = edge[NE + e];
  int pos = rowptr[r] + atomicAdd(&fill[r], 1);
  colsorted[pos] = c;
}

// ---------------- W pre-convert: fp32 -> tiled bf16 hi/lo ----------------
// Wt layout: [kt][col][kk] with kt=k/32, kk=k%32 -> flat kt*8192 + col*32 + kk
__global__ __launch_bounds__(256) void wcvt(const float* __restrict__ W,
                                            unsigned short* __restrict__ wt_hi,
                                            unsigned short* __restrict__ wt_lo) {
  int i = blockIdx.x * 256 + threadIdx.x;
  if (i >= KDIM * CDIM) return;
  int kt = i >> 13, rem = i & 8191, col = rem >> 5, kk = rem & 31;
  float v = W[(size_t)(kt * 32 + kk) * CDIM + col];
  unsigned short hi = f2bf(v);
  float r = v - bf2f(hi);
  wt_hi[i] = hi;
  wt_lo[i] = f2bf(r);
}

// ---------------- fused projection: bf16x3 MFMA GEMM + logits + bf16 h ----
// Block: 256 thr (4 waves), BM=64 rows, BN=256 (full width; wave wid owns
// cols wid*64..+64 = head wid). K-loop: 8 steps of BK=32.
// LDS: A_hi[64][40], A_lo[64][40], Bt_hi[256][40], Bt_lo[256][40]  (pad 40
// makes frag ds_read_b128 bank-uniform). Epilogue reuses LDS: per-wave
// c_tile[64][72] bf16 for coalesced hb stores.
#define LDS_AHI 0
#define LDS_ALO 2560
#define LDS_BHI 5120
#define LDS_BLO 15360
#define LDS_TOT 25600

__global__ __launch_bounds__(256) void gemm_fused(const float* __restrict__ X,
                                                  const unsigned short* __restrict__ wt_hi,
                                                  const unsigned short* __restrict__ wt_lo,
                                                  const float* __restrict__ al,
                                                  const float* __restrict__ ar,
                                                  unsigned short* __restrict__ hb,
                                                  float* __restrict__ hl,
                                                  float* __restrict__ hr, int M) {
  __shared__ unsigned short lds[LDS_TOT];
  const int tid = threadIdx.x;
  const int lane = tid & 63;
  const int wid = tid >> 6;            // wave = head = col block
  const int row0 = blockIdx.x * 64;
  const int frow = lane & 15;          // fragment row/col within 16
  const int fk = (lane >> 4) * 8;      // fragment k-chunk
  const int arow = tid >> 2;           // staging: A row (0..63)
  const int akc = (tid & 3) * 8;       // staging: A k-chunk (0,8,16,24)

  f32x4 acc[4][4] = {};                // [mi][ni]

  for (int kt = 0; kt < 8; ++kt) {
    // ---- load A tile (fp32, convert to hi/lo) ----
    float va[8];
    {
      int gr = row0 + arow;
      float4 a0 = make_float4(0.f, 0.f, 0.f, 0.f), a1 = a0;
      if (gr < M) {
        const float* p = &X[(size_t)gr * KDIM + kt * 32 + akc];
        a0 = *(const float4*)p;
        a1 = *(const float4*)(p + 4);
      }
      va[0] = a0.x; va[1] = a0.y; va[2] = a0.z; va[3] = a0.w;
      va[4] = a1.x; va[5] = a1.y; va[6] = a1.z; va[7] = a1.w;
    }
    // ---- load B tile (pre-converted bf16, tiled => fully coalesced) ----
    uint4 bh[4], bl[4];
#pragma unroll
    for (int j = 0; j < 4; ++j) {
      int flat = j * 2048 + tid * 8;
      bh[j] = *(const uint4*)&wt_hi[kt * 8192 + flat];
      bl[j] = *(const uint4*)&wt_lo[kt * 8192 + flat];
    }
    __syncthreads();   // previous iter's frag reads complete
    {
      bh8 ahi, alo;
#pragma unroll
      for (int j = 0; j < 8; ++j) {
        unsigned short h = f2bf(va[j]);
        ahi[j] = (short)h;
        alo[j] = (short)f2bf(va[j] - bf2f(h));
      }
      *(bh8*)&lds[LDS_AHI + arow * 40 + akc] = ahi;
      *(bh8*)&lds[LDS_ALO + arow * 40 + akc] = alo;
    }
#pragma unroll
    for (int j = 0; j < 4; ++j) {
      int flat = j * 2048 + tid * 8;
      int col = flat >> 5, kk = flat & 31;
      *(uint4*)&lds[LDS_BHI + col * 40 + kk] = bh[j];
      *(uint4*)&lds[LDS_BLO + col * 40 + kk] = bl[j];
    }
    __syncthreads();
    // ---- fragments + MFMA (bf16x3: hi*hi + hi*lo + lo*hi) ----
    bh8 fah[4], fal[4], fbh[4], fbl[4];
#pragma unroll
    for (int mi = 0; mi < 4; ++mi) {
      fah[mi] = *(const bh8*)&lds[LDS_AHI + (mi * 16 + frow) * 40 + fk];
      fal[mi] = *(const bh8*)&lds[LDS_ALO + (mi * 16 + frow) * 40 + fk];
    }
#pragma unroll
    for (int ni = 0; ni < 4; ++ni) {
      int c = wid * 64 + ni * 16 + frow;
      fbh[ni] = *(const bh8*)&lds[LDS_BHI + c * 40 + fk];
      fbl[ni] = *(const bh8*)&lds[LDS_BLO + c * 40 + fk];
    }
#pragma unroll
    for (int mi = 0; mi < 4; ++mi)
#pragma unroll
      for (int ni = 0; ni < 4; ++ni) {
        acc[mi][ni] = __builtin_amdgcn_mfma_f32_16x16x32_bf16(fah[mi], fbh[ni], acc[mi][ni], 0, 0, 0);
        acc[mi][ni] = __builtin_amdgcn_mfma_f32_16x16x32_bf16(fah[mi], fbl[ni], acc[mi][ni], 0, 0, 0);
        acc[mi][ni] = __builtin_amdgcn_mfma_f32_16x16x32_bf16(fal[mi], fbh[ni], acc[mi][ni], 0, 0, 0);
      }
  }

  // ---- epilogue 1: hl/hr from fp32 accumulators ----
  // D layout: col = ni*16 + (lane&15), row = mi*16 + (lane>>4)*4 + reg
  float alv[4], arv[4];
#pragma unroll
  for (int ni = 0; ni < 4; ++ni) {
    alv[ni] = al[wid * 64 + ni * 16 + frow];
    arv[ni] = ar[wid * 64 + ni * 16 + frow];
  }
#pragma unroll
  for (int mi = 0; mi < 4; ++mi) {
#pragma unroll
    for (int rg = 0; rg < 4; ++rg) {
      float sl = 0.f, sr = 0.f;
#pragma unroll
      for (int ni = 0; ni < 4; ++ni) {
        float cv = acc[mi][ni][rg];
        sl += cv * alv[ni];
        sr += cv * arv[ni];
      }
#pragma unroll
      for (int off = 1; off < 16; off <<= 1) {
        sl += __shfl_xor(sl, off);
        sr += __shfl_xor(sr, off);
      }
      int r = row0 + mi * 16 + (lane >> 4) * 4 + rg;
      if ((lane & 15) == 0 && r < M) {
        hl[(size_t)r * 4 + wid] = sl;
        hr[(size_t)r * 4 + wid] = sr;
      }
    }
  }

  // ---- epilogue 2: hb (bf16 h) via LDS repack for coalesced stores ----
  __syncthreads();   // all waves done with A/B tiles
  const int cbase = wid * 4608;   // c_tile[64][72]
#pragma unroll
  for (int mi = 0; mi < 4; ++mi)
#pragma unroll
    for (int ni = 0; ni < 4; ++ni)
#pragma unroll
      for (int rg = 0; rg < 4; ++rg)
        lds[cbase + (mi * 16 + (lane >> 4) * 4 + rg) * 72 + ni * 16 + frow] =
            f2bf(acc[mi][ni][rg]);
  __syncthreads();
#pragma unroll
  for (int it = 0; it < 8; ++it) {
    int chunk = it * 64 + lane;
    int rr = chunk >> 3, cc = chunk & 7;
    uint4 v = *(const uint4*)&lds[cbase + rr * 72 + cc * 8];
    int grr = row0 + rr;
    if (grr < M)
      *(uint4*)&hb[(size_t)grr * CDIM + wid * 64 + cc * 8] = v;
  }
}

// ---------------- fused per-row softmax+aggregate (wave per row) ----------------
__global__ __launch_bounds__(256) void row_aggregate(const int* __restrict__ rowptr,
                                                     const int* __restrict__ colsorted,
                                                     const float* __restrict__ hl,
                                                     const float* __restrict__ hr,
                                                     const unsigned short* __restrict__ hb,
                                                     float* __restrict__ out) {
  int wid = (int)((blockIdx.x * 256 + threadIdx.x) >> 6);
  int lane = threadIdx.x & 63;
  if (wid >= NN) return;
  int s = rowptr[wid], e = rowptr[wid + 1];
  int head = lane >> 4;
  float hlv = hl[(size_t)wid * 4 + head];
  float4 acc = make_float4(0.f, 0.f, 0.f, 0.f);
  float den = 0.f;
  for (int i = s; i < e; ++i) {
    int c = colsorted[i];                             // wave-uniform broadcast
    float sc = hlv + hr[(size_t)c * 4 + head];
    sc = sc > 0.f ? sc : ALPHA * sc;
    float ee = __expf(sc);
    den += ee;
    ushort4 u = *(const ushort4*)&hb[(size_t)c * CDIM + lane * 4];
    float4 hv = bf4_to_f4(u);
    acc.x += ee * hv.x; acc.y += ee * hv.y; acc.z += ee * hv.z; acc.w += ee * hv.w;
  }
  float rd = den > 0.f ? 1.f / den : 0.f;
  acc.x *= rd; acc.y *= rd; acc.z *= rd; acc.w *= rd;
  *(float4*)&out[(size_t)wid * CDIM + lane * 4] = acc;
}

// ---------------- launch ----------------

extern "C" void kernel_launch(void* const* d_in, const int* in_sizes, int n_in,
                              void* d_out, int out_size, void* d_ws, size_t ws_size,
                              hipStream_t stream) {
  const float* x   = (const float*)d_in[0];
  const int*  edge = (const int*)d_in[1];
  const float* W   = (const float*)d_in[2];
  const float* al  = (const float*)d_in[3];
  const float* ar  = (const float*)d_in[4];
  float* out = (float*)d_out;

  char* base = (char*)d_ws;
  unsigned short* hb = (unsigned short*)base;                    // NN*256 bf16 = 25.6MB
  float* hl = (float*)(base + (size_t)NN * CDIM * 2);            // NN*4
  float* hr = hl + (size_t)NN * NHEAD;                           // NN*4
  unsigned short* wt_hi = (unsigned short*)(hr + (size_t)NN * NHEAD);  // 65536
  unsigned short* wt_lo = wt_hi + KDIM * CDIM;                   // 65536
  int* deg       = (int*)(wt_lo + KDIM * CDIM);                  // NN
  int* fill      = deg + NN;                                     // NN
  int* rowptr    = fill + NN;                                    // NN+1
  int* partials  = rowptr + NN + 1;                              // 64
  int* colsorted = partials + 64;                                // NE

  hipMemsetAsync(deg, 0, (size_t)2 * NN * sizeof(int), stream);  // deg + fill

  deg_count<<<(NE + 255) / 256, 256, 0, stream>>>(edge, deg);
  scan_blocks<<<SCAN_NBLK, 256, 0, stream>>>(deg, rowptr, partials);
  scan_partials<<<1, 64, 0, stream>>>(partials);
  scan_add<<<(NN + 255) / 256, 256, 0, stream>>>(rowptr, partials);
  scatter_edges<<<(NE + 255) / 256, 256, 0, stream>>>(edge, rowptr, fill, colsorted);

  wcvt<<<(KDIM * CDIM + 255) / 256, 256, 0, stream>>>(W, wt_hi, wt_lo);
  gemm_fused<<<(NN + 63) / 64, 256, 0, stream>>>(x, wt_hi, wt_lo, al, ar, hb, hl, hr, NN);

  row_aggregate<<<(NN * 64 + 255) / 256, 256, 0, stream>>>(rowptr, colsorted, hl, hr, hb, out);
}

// Round 7
// 311.409 us; speedup vs baseline: 10.1830x; 1.1974x over previous
//
#include <hip/hip_runtime.h>
#include <math.h>

#define NN 50000
#define NE 800000
#define KDIM 256      // IN_F
#define CDIM 256      // NHEAD*OUT_F
#define NHEAD 4
#define HF 64         // OUT_F
#define ALPHA 0.2f
#define SCAN_NBLK ((NN + 1023) / 1024)   // 49

typedef short bh8 __attribute__((ext_vector_type(8)));   // 8 bf16 (4 VGPR)
typedef float f32x4 __attribute__((ext_vector_type(4)));

// ---------------- helpers ----------------

__device__ __forceinline__ unsigned short f2bf(float f) {  // RNE bf16
  unsigned u = __float_as_uint(f);
  return (unsigned short)((u + 0x7FFFu + ((u >> 16) & 1u)) >> 16);
}
__device__ __forceinline__ float bf2f(unsigned short u) {
  return __uint_as_float((unsigned)u << 16);
}
__device__ __forceinline__ float4 bf4_to_f4(ushort4 u) {
  float4 r;
  r.x = bf2f(u.x); r.y = bf2f(u.y); r.z = bf2f(u.z); r.w = bf2f(u.w);
  return r;
}

// ---------------- CSR build (+ fused W convert) ----------------
// wt layout: [nb(2)][kt(8)][col(128)][kk(32)] tight; block-coalesced for GEMM.
__global__ __launch_bounds__(256) void deg_count_wcvt(const int* __restrict__ edge,
                                                      int* __restrict__ deg,
                                                      const float* __restrict__ W,
                                                      unsigned short* __restrict__ wt_hi,
                                                      unsigned short* __restrict__ wt_lo) {
  int e = blockIdx.x * 256 + threadIdx.x;
  if (e < NE) atomicAdd(&deg[edge[e]], 1);
  if (e < KDIM * CDIM) {               // first 256 blocks: one W row each
    int gcol = e & 255, k = e >> 8;    // tid = gcol -> coalesced W read
    int nb = gcol >> 7, col = gcol & 127, kt = k >> 5, kk = k & 31;
    float v = W[(size_t)k * CDIM + gcol];
    unsigned short hi = f2bf(v);
    int dst = (nb * 8 + kt) * 4096 + col * 32 + kk;
    wt_hi[dst] = hi;
    wt_lo[dst] = f2bf(v - bf2f(hi));
  }
}

__global__ __launch_bounds__(256) void scan_blocks(const int* __restrict__ deg,
                                                   int* __restrict__ rowptr,
                                                   int* __restrict__ partials) {
  __shared__ int sc[256];
  int t = threadIdx.x;
  int base = blockIdx.x * 1024 + t * 4;
  int v[4];
#pragma unroll
  for (int i = 0; i < 4; ++i) v[i] = (base + i < NN) ? deg[base + i] : 0;
  int tsum = v[0] + v[1] + v[2] + v[3];
  sc[t] = tsum;
  __syncthreads();
  for (int off = 1; off < 256; off <<= 1) {
    int x = sc[t];
    int y = (t >= off) ? sc[t - off] : 0;
    __syncthreads();
    sc[t] = x + y;
    __syncthreads();
  }
  if (t == 255) partials[blockIdx.x] = sc[255];
  int run = (t > 0) ? sc[t - 1] : 0;
#pragma unroll
  for (int i = 0; i < 4; ++i) {
    if (base + i < NN) rowptr[base + i] = run;
    run += v[i];
  }
}

__global__ void scan_partials(int* __restrict__ partials) {
  if (threadIdx.x == 0) {
    int run = 0;
    for (int i = 0; i < SCAN_NBLK; ++i) { int v = partials[i]; partials[i] = run; run += v; }
  }
}

__global__ __launch_bounds__(256) void scan_add(int* __restrict__ rowptr,
                                                const int* __restrict__ partials) {
  int i = blockIdx.x * 256 + threadIdx.x;
  if (i < NN) rowptr[i] += partials[i >> 10];
  if (i == 0) rowptr[NN] = NE;
}

__global__ __launch_bounds__(256) void scatter_edges(const int* __restrict__ edge,
                                                     const int* __restrict__ rowptr,
                                                     int* __restrict__ fill,
                                                     int* __restrict__ colsorted) {
  int e = blockIdx.x * 256 + threadIdx.x;
  if (e >= NE) return;
  int r = edge[e], c = edge[NE + e];
  int pos = rowptr[r] + atomicAdd(&fill[r], 1);
  colsorted[pos] = c;
}

// ---------------- fused projection: bf16x3 MFMA GEMM + logits + bf16 h ----
// Grid (2, ceil(NN/64)); 256 thr = 4 waves in 2x2 (wm = M-half, wn = N-half).
// Block tile 64 rows x 128 cols; wave tile 32x64 (= one head's cols) ->
// acc 2x4 f32x4 = 32 VGPRs, no spill. LDS 30.7KB (5 blocks/CU cap).
#define LDS_AHI 0
#define LDS_ALO 2560
#define LDS_BHI 5120
#define LDS_BLO 10240
#define LDS_TOT 15360

__global__ __launch_bounds__(256, 2) void gemm_fused(const float* __restrict__ X,
                                                     const unsigned short* __restrict__ wt_hi,
                                                     const unsigned short* __restrict__ wt_lo,
                                                     const float* __restrict__ al,
                                                     const float* __restrict__ ar,
                                                     unsigned short* __restrict__ hb,
                                                     float* __restrict__ hl,
                                                     float* __restrict__ hr, int M) {
  __shared__ unsigned short lds[LDS_TOT];
  const int tid = threadIdx.x;
  const int lane = tid & 63;
  const int wid = tid >> 6;
  const int wm = wid >> 1, wn = wid & 1;
  const int nb = blockIdx.x;           // N-half (2 heads)
  const int row0 = blockIdx.y * 64;
  const int frow = lane & 15;          // fragment row/col within 16
  const int fk = (lane >> 4) * 8;      // fragment k-chunk
  const int arow = tid >> 2;           // staging: A row (0..63)
  const int akc = (tid & 3) * 8;       // staging: A k-chunk
  const int hd = nb * 2 + wn;          // this wave's head

  f32x4 acc[2][4] = {};                // [mi][ni]

  for (int kt = 0; kt < 8; ++kt) {
    // ---- issue global loads ----
    float4 a0 = make_float4(0.f, 0.f, 0.f, 0.f), a1 = a0;
    {
      int gr = row0 + arow;
      if (gr < M) {
        const float* p = &X[(size_t)gr * KDIM + kt * 32 + akc];
        a0 = *(const float4*)p;
        a1 = *(const float4*)(p + 4);
      }
    }
    const int bbase = (nb * 8 + kt) * 4096;
    uint4 b0h = *(const uint4*)&wt_hi[bbase + tid * 8];
    uint4 b1h = *(const uint4*)&wt_hi[bbase + 2048 + tid * 8];
    uint4 b0l = *(const uint4*)&wt_lo[bbase + tid * 8];
    uint4 b1l = *(const uint4*)&wt_lo[bbase + 2048 + tid * 8];
    __syncthreads();   // previous iter's frag reads complete
    // ---- A convert + LDS write ----
    {
      float va[8] = {a0.x, a0.y, a0.z, a0.w, a1.x, a1.y, a1.z, a1.w};
      bh8 ahi, alo;
#pragma unroll
      for (int j = 0; j < 8; ++j) {
        unsigned short h = f2bf(va[j]);
        ahi[j] = (short)h;
        alo[j] = (short)f2bf(va[j] - bf2f(h));
      }
      *(bh8*)&lds[LDS_AHI + arow * 40 + akc] = ahi;
      *(bh8*)&lds[LDS_ALO + arow * 40 + akc] = alo;
    }
    // ---- B LDS write (padded 40 stride for conflict-light frag reads) ----
    {
      int f0 = tid * 8, c0 = f0 >> 5, k0 = f0 & 31;
      *(uint4*)&lds[LDS_BHI + c0 * 40 + k0] = b0h;
      *(uint4*)&lds[LDS_BLO + c0 * 40 + k0] = b0l;
      int f1 = 2048 + tid * 8, c1 = f1 >> 5, k1 = f1 & 31;
      *(uint4*)&lds[LDS_BHI + c1 * 40 + k1] = b1h;
      *(uint4*)&lds[LDS_BLO + c1 * 40 + k1] = b1l;
    }
    __syncthreads();
    // ---- fragments + MFMA (bf16x3: hi*hi + hi*lo + lo*hi) ----
    bh8 fah[2], fal[2];
#pragma unroll
    for (int mi = 0; mi < 2; ++mi) {
      fah[mi] = *(const bh8*)&lds[LDS_AHI + (wm * 32 + mi * 16 + frow) * 40 + fk];
      fal[mi] = *(const bh8*)&lds[LDS_ALO + (wm * 32 + mi * 16 + frow) * 40 + fk];
    }
#pragma unroll
    for (int ni = 0; ni < 4; ++ni) {
      int c = wn * 64 + ni * 16 + frow;
      bh8 fbh = *(const bh8*)&lds[LDS_BHI + c * 40 + fk];
      bh8 fbl = *(const bh8*)&lds[LDS_BLO + c * 40 + fk];
#pragma unroll
      for (int mi = 0; mi < 2; ++mi) {
        acc[mi][ni] = __builtin_amdgcn_mfma_f32_16x16x32_bf16(fah[mi], fbh, acc[mi][ni], 0, 0, 0);
        acc[mi][ni] = __builtin_amdgcn_mfma_f32_16x16x32_bf16(fah[mi], fbl, acc[mi][ni], 0, 0, 0);
        acc[mi][ni] = __builtin_amdgcn_mfma_f32_16x16x32_bf16(fal[mi], fbh, acc[mi][ni], 0, 0, 0);
      }
    }
  }

  // ---- epilogue 1: hl/hr from fp32 accumulators ----
  // D layout per tile: col = lane&15, row = (lane>>4)*4 + reg
  float alv[4], arv[4];
#pragma unroll
  for (int ni = 0; ni < 4; ++ni) {
    alv[ni] = al[hd * 64 + ni * 16 + frow];
    arv[ni] = ar[hd * 64 + ni * 16 + frow];
  }
#pragma unroll
  for (int mi = 0; mi < 2; ++mi) {
#pragma unroll
    for (int rg = 0; rg < 4; ++rg) {
      float sl = 0.f, sr = 0.f;
#pragma unroll
      for (int ni = 0; ni < 4; ++ni) {
        float cv = acc[mi][ni][rg];
        sl += cv * alv[ni];
        sr += cv * arv[ni];
      }
#pragma unroll
      for (int off = 1; off < 16; off <<= 1) {
        sl += __shfl_xor(sl, off);
        sr += __shfl_xor(sr, off);
      }
      int r = row0 + wm * 32 + mi * 16 + (lane >> 4) * 4 + rg;
      if ((lane & 15) == 0 && r < M) {
        hl[(size_t)r * 4 + hd] = sl;
        hr[(size_t)r * 4 + hd] = sr;
      }
    }
  }

  // ---- epilogue 2: hb (bf16 h) via LDS repack for coalesced stores ----
  __syncthreads();   // all waves done with A/B tiles
  const int cbase = wid * 2304;   // c_tile[32][72] per wave
#pragma unroll
  for (int mi = 0; mi < 2; ++mi)
#pragma unroll
    for (int ni = 0; ni < 4; ++ni)
#pragma unroll
      for (int rg = 0; rg < 4; ++rg)
        lds[cbase + (mi * 16 + (lane >> 4) * 4 + rg) * 72 + ni * 16 + frow] =
            f2bf(acc[mi][ni][rg]);
  __syncthreads();
#pragma unroll
  for (int it = 0; it < 4; ++it) {
    int chunk = it * 64 + lane;
    int rr = chunk >> 3, cc = chunk & 7;
    uint4 v = *(const uint4*)&lds[cbase + rr * 72 + cc * 8];
    int grr = row0 + wm * 32 + rr;
    if (grr < M)
      *(uint4*)&hb[(size_t)grr * CDIM + hd * 64 + cc * 8] = v;
  }
}

// ---------------- fused per-row softmax+aggregate (wave per row) ----------------
__global__ __launch_bounds__(256) void row_aggregate(const int* __restrict__ rowptr,
                                                     const int* __restrict__ colsorted,
                                                     const float* __restrict__ hl,
                                                     const float* __restrict__ hr,
                                                     const unsigned short* __restrict__ hb,
                                                     float* __restrict__ out) {
  int wid = (int)((blockIdx.x * 256 + threadIdx.x) >> 6);
  int lane = threadIdx.x & 63;
  if (wid >= NN) return;
  int s = rowptr[wid], e = rowptr[wid + 1];
  int head = lane >> 4;
  float hlv = hl[(size_t)wid * 4 + head];
  float4 acc = make_float4(0.f, 0.f, 0.f, 0.f);
  float den = 0.f;
  for (int i = s; i < e; ++i) {
    int c = colsorted[i];                             // wave-uniform broadcast
    float sc = hlv + hr[(size_t)c * 4 + head];
    sc = sc > 0.f ? sc : ALPHA * sc;
    float ee = __expf(sc);
    den += ee;
    ushort4 u = *(const ushort4*)&hb[(size_t)c * CDIM + lane * 4];
    float4 hv = bf4_to_f4(u);
    acc.x += ee * hv.x; acc.y += ee * hv.y; acc.z += ee * hv.z; acc.w += ee * hv.w;
  }
  float rd = den > 0.f ? 1.f / den : 0.f;
  acc.x *= rd; acc.y *= rd; acc.z *= rd; acc.w *= rd;
  *(float4*)&out[(size_t)wid * CDIM + lane * 4] = acc;
}

// ---------------- launch ----------------

extern "C" void kernel_launch(void* const* d_in, const int* in_sizes, int n_in,
                              void* d_out, int out_size, void* d_ws, size_t ws_size,
                              hipStream_t stream) {
  const float* x   = (const float*)d_in[0];
  const int*  edge = (const int*)d_in[1];
  const float* W   = (const float*)d_in[2];
  const float* al  = (const float*)d_in[3];
  const float* ar  = (const float*)d_in[4];
  float* out = (float*)d_out;

  char* base = (char*)d_ws;
  unsigned short* hb = (unsigned short*)base;                    // NN*256 bf16 = 25.6MB
  float* hl = (float*)(base + (size_t)NN * CDIM * 2);            // NN*4
  float* hr = hl + (size_t)NN * NHEAD;                           // NN*4
  unsigned short* wt_hi = (unsigned short*)(hr + (size_t)NN * NHEAD);  // 65536
  unsigned short* wt_lo = wt_hi + KDIM * CDIM;                   // 65536
  int* deg       = (int*)(wt_lo + KDIM * CDIM);                  // NN
  int* fill      = deg + NN;                                     // NN
  int* rowptr    = fill + NN;                                    // NN+1
  int* partials  = rowptr + NN + 1;                              // 64
  int* colsorted = partials + 64;                                // NE

  hipMemsetAsync(deg, 0, (size_t)2 * NN * sizeof(int), stream);  // deg + fill

  deg_count_wcvt<<<(NE + 255) / 256, 256, 0, stream>>>(edge, deg, W, wt_hi, wt_lo);
  scan_blocks<<<SCAN_NBLK, 256, 0, stream>>>(deg, rowptr, partials);
  scan_partials<<<1, 64, 0, stream>>>(partials);
  scan_add<<<(NN + 255) / 256, 256, 0, stream>>>(rowptr, partials);
  scatter_edges<<<(NE + 255) / 256, 256, 0, stream>>>(edge, rowptr, fill, colsorted);

  gemm_fused<<<dim3(2, (NN + 63) / 64), 256, 0, stream>>>(x, wt_hi, wt_lo, al, ar, hb, hl, hr, NN);

  row_aggregate<<<(NN * 64 + 255) / 256, 256, 0, stream>>>(rowptr, colsorted, hl, hr, hb, out);
}

// Round 8
// 302.641 us; speedup vs baseline: 10.4780x; 1.0290x over previous
//
#include <hip/hip_runtime.h>
#include <math.h>

#define NN 50000
#define NE 800000
#define KDIM 256      // IN_F
#define CDIM 256      // NHEAD*OUT_F
#define NHEAD 4
#define HF 64         // OUT_F
#define ALPHA 0.2f

typedef short bh8 __attribute__((ext_vector_type(8)));   // 8 bf16 (4 VGPR)
typedef float f32x4 __attribute__((ext_vector_type(4)));

// ---------------- helpers ----------------

__device__ __forceinline__ unsigned short f2bf(float f) {  // RNE bf16
  unsigned u = __float_as_uint(f);
  return (unsigned short)((u + 0x7FFFu + ((u >> 16) & 1u)) >> 16);
}
__device__ __forceinline__ float bf2f(unsigned short u) {
  return __uint_as_float((unsigned)u << 16);
}
__device__ __forceinline__ float4 bf4_to_f4(ushort4 u) {
  float4 r;
  r.x = bf2f(u.x); r.y = bf2f(u.y); r.z = bf2f(u.z); r.w = bf2f(u.w);
  return r;
}

// ---------------- CSR build (+ fused W convert) ----------------
// wt layout: [nb(2)][kt(8)][col(128)][kk(32)] tight; block-coalesced for GEMM.
__global__ __launch_bounds__(256) void deg_count_wcvt(const int* __restrict__ edge,
                                                      int* __restrict__ deg,
                                                      const float* __restrict__ W,
                                                      unsigned short* __restrict__ wt_hi,
                                                      unsigned short* __restrict__ wt_lo) {
  int e = blockIdx.x * 256 + threadIdx.x;
  if (e < NE) atomicAdd(&deg[edge[e]], 1);
  if (e < KDIM * CDIM) {               // first 256 blocks: one W row each
    int gcol = e & 255, k = e >> 8;    // tid = gcol -> coalesced W read
    int nb = gcol >> 7, col = gcol & 127, kt = k >> 5, kk = k & 31;
    float v = W[(size_t)k * CDIM + gcol];
    unsigned short hi = f2bf(v);
    int dst = (nb * 8 + kt) * 4096 + col * 32 + kk;
    wt_hi[dst] = hi;
    wt_lo[dst] = f2bf(v - bf2f(hi));
  }
}

// single-workgroup full exclusive scan of deg[NN] -> rowptr (1024 thr, 13 int4 each)
#define SCH 13
__global__ __launch_bounds__(1024) void scan_all(const int* __restrict__ deg,
                                                 int* __restrict__ rowptr) {
  __shared__ int sums[1024];
  const int t = threadIdx.x;
  const int base = t * (SCH * 4);
  int4 v[SCH];
  int s = 0;
#pragma unroll
  for (int i = 0; i < SCH; ++i) {
    int idx = base + i * 4;
    int4 x = make_int4(0, 0, 0, 0);
    if (idx + 3 < NN) {
      x = *(const int4*)&deg[idx];
    } else {
      if (idx + 0 < NN) x.x = deg[idx + 0];
      if (idx + 1 < NN) x.y = deg[idx + 1];
      if (idx + 2 < NN) x.z = deg[idx + 2];
      if (idx + 3 < NN) x.w = deg[idx + 3];
    }
    v[i] = x;
    s += x.x + x.y + x.z + x.w;
  }
  sums[t] = s;
  __syncthreads();
  for (int off = 1; off < 1024; off <<= 1) {
    int x = sums[t];
    int y = (t >= off) ? sums[t - off] : 0;
    __syncthreads();
    sums[t] = x + y;
    __syncthreads();
  }
  int run = (t > 0) ? sums[t - 1] : 0;
#pragma unroll
  for (int i = 0; i < SCH; ++i) {
    int idx = base + i * 4;
    int4 x = v[i];
    if (idx + 0 < NN) rowptr[idx + 0] = run;
    run += x.x;
    if (idx + 1 < NN) rowptr[idx + 1] = run;
    run += x.y;
    if (idx + 2 < NN) rowptr[idx + 2] = run;
    run += x.z;
    if (idx + 3 < NN) rowptr[idx + 3] = run;
    run += x.w;
  }
  if (t == 0) rowptr[NN] = NE;
}

// scatter edges into row-sorted order; deg is consumed (atomicSub) as the fill
__global__ __launch_bounds__(256) void scatter_edges(const int* __restrict__ edge,
                                                     const int* __restrict__ rowptr,
                                                     int* __restrict__ deg,
                                                     int* __restrict__ colsorted) {
  int e = blockIdx.x * 256 + threadIdx.x;
  if (e >= NE) return;
  int r = edge[e], c = edge[NE + e];
  int pos = rowptr[r] + atomicSub(&deg[r], 1) - 1;
  colsorted[pos] = c;
}

// ---------------- fused projection: bf16x3 MFMA GEMM + logits + bf16 h ----
// Grid (2, ceil(NN/64)); 256 thr = 4 waves in 2x2 (wm = M-half, wn = N-half).
// Block tile 64 rows x 128 cols; wave tile 32x64 (= one head's cols).
#define LDS_AHI 0
#define LDS_ALO 2560
#define LDS_BHI 5120
#define LDS_BLO 10240
#define LDS_TOT 15360

__global__ __launch_bounds__(256, 2) void gemm_fused(const float* __restrict__ X,
                                                     const unsigned short* __restrict__ wt_hi,
                                                     const unsigned short* __restrict__ wt_lo,
                                                     const float* __restrict__ al,
                                                     const float* __restrict__ ar,
                                                     unsigned short* __restrict__ hb,
                                                     float* __restrict__ hl,
                                                     float* __restrict__ hr, int M) {
  __shared__ unsigned short lds[LDS_TOT];
  const int tid = threadIdx.x;
  const int lane = tid & 63;
  const int wid = tid >> 6;
  const int wm = wid >> 1, wn = wid & 1;
  const int nb = blockIdx.x;           // N-half (2 heads)
  const int row0 = blockIdx.y * 64;
  const int frow = lane & 15;          // fragment row/col within 16
  const int fk = (lane >> 4) * 8;      // fragment k-chunk
  const int arow = tid >> 2;           // staging: A row (0..63)
  const int akc = (tid & 3) * 8;       // staging: A k-chunk
  const int hd = nb * 2 + wn;          // this wave's head

  f32x4 acc[2][4] = {};                // [mi][ni]

  for (int kt = 0; kt < 8; ++kt) {
    float4 a0 = make_float4(0.f, 0.f, 0.f, 0.f), a1 = a0;
    {
      int gr = row0 + arow;
      if (gr < M) {
        const float* p = &X[(size_t)gr * KDIM + kt * 32 + akc];
        a0 = *(const float4*)p;
        a1 = *(const float4*)(p + 4);
      }
    }
    const int bbase = (nb * 8 + kt) * 4096;
    uint4 b0h = *(const uint4*)&wt_hi[bbase + tid * 8];
    uint4 b1h = *(const uint4*)&wt_hi[bbase + 2048 + tid * 8];
    uint4 b0l = *(const uint4*)&wt_lo[bbase + tid * 8];
    uint4 b1l = *(const uint4*)&wt_lo[bbase + 2048 + tid * 8];
    __syncthreads();   // previous iter's frag reads complete
    {
      float va[8] = {a0.x, a0.y, a0.z, a0.w, a1.x, a1.y, a1.z, a1.w};
      bh8 ahi, alo;
#pragma unroll
      for (int j = 0; j < 8; ++j) {
        unsigned short h = f2bf(va[j]);
        ahi[j] = (short)h;
        alo[j] = (short)f2bf(va[j] - bf2f(h));
      }
      *(bh8*)&lds[LDS_AHI + arow * 40 + akc] = ahi;
      *(bh8*)&lds[LDS_ALO + arow * 40 + akc] = alo;
    }
    {
      int f0 = tid * 8, c0 = f0 >> 5, k0 = f0 & 31;
      *(uint4*)&lds[LDS_BHI + c0 * 40 + k0] = b0h;
      *(uint4*)&lds[LDS_BLO + c0 * 40 + k0] = b0l;
      int f1 = 2048 + tid * 8, c1 = f1 >> 5, k1 = f1 & 31;
      *(uint4*)&lds[LDS_BHI + c1 * 40 + k1] = b1h;
      *(uint4*)&lds[LDS_BLO + c1 * 40 + k1] = b1l;
    }
    __syncthreads();
    bh8 fah[2], fal[2];
#pragma unroll
    for (int mi = 0; mi < 2; ++mi) {
      fah[mi] = *(const bh8*)&lds[LDS_AHI + (wm * 32 + mi * 16 + frow) * 40 + fk];
      fal[mi] = *(const bh8*)&lds[LDS_ALO + (wm * 32 + mi * 16 + frow) * 40 + fk];
    }
#pragma unroll
    for (int ni = 0; ni < 4; ++ni) {
      int c = wn * 64 + ni * 16 + frow;
      bh8 fbh = *(const bh8*)&lds[LDS_BHI + c * 40 + fk];
      bh8 fbl = *(const bh8*)&lds[LDS_BLO + c * 40 + fk];
#pragma unroll
      for (int mi = 0; mi < 2; ++mi) {
        acc[mi][ni] = __builtin_amdgcn_mfma_f32_16x16x32_bf16(fah[mi], fbh, acc[mi][ni], 0, 0, 0);
        acc[mi][ni] = __builtin_amdgcn_mfma_f32_16x16x32_bf16(fah[mi], fbl, acc[mi][ni], 0, 0, 0);
        acc[mi][ni] = __builtin_amdgcn_mfma_f32_16x16x32_bf16(fal[mi], fbh, acc[mi][ni], 0, 0, 0);
      }
    }
  }

  // ---- epilogue 1: hl/hr from fp32 accumulators ----
  float alv[4], arv[4];
#pragma unroll
  for (int ni = 0; ni < 4; ++ni) {
    alv[ni] = al[hd * 64 + ni * 16 + frow];
    arv[ni] = ar[hd * 64 + ni * 16 + frow];
  }
#pragma unroll
  for (int mi = 0; mi < 2; ++mi) {
#pragma unroll
    for (int rg = 0; rg < 4; ++rg) {
      float sl = 0.f, sr = 0.f;
#pragma unroll
      for (int ni = 0; ni < 4; ++ni) {
        float cv = acc[mi][ni][rg];
        sl += cv * alv[ni];
        sr += cv * arv[ni];
      }
#pragma unroll
      for (int off = 1; off < 16; off <<= 1) {
        sl += __shfl_xor(sl, off);
        sr += __shfl_xor(sr, off);
      }
      int r = row0 + wm * 32 + mi * 16 + (lane >> 4) * 4 + rg;
      if ((lane & 15) == 0 && r < M) {
        hl[(size_t)r * 4 + hd] = sl;
        hr[(size_t)r * 4 + hd] = sr;
      }
    }
  }

  // ---- epilogue 2: hb (bf16 h) via LDS repack for coalesced stores ----
  __syncthreads();
  const int cbase = wid * 2304;   // c_tile[32][72] per wave
#pragma unroll
  for (int mi = 0; mi < 2; ++mi)
#pragma unroll
    for (int ni = 0; ni < 4; ++ni)
#pragma unroll
      for (int rg = 0; rg < 4; ++rg)
        lds[cbase + (mi * 16 + (lane >> 4) * 4 + rg) * 72 + ni * 16 + frow] =
            f2bf(acc[mi][ni][rg]);
  __syncthreads();
#pragma unroll
  for (int it = 0; it < 4; ++it) {
    int chunk = it * 64 + lane;
    int rr = chunk >> 3, cc = chunk & 7;
    uint4 v = *(const uint4*)&lds[cbase + rr * 72 + cc * 8];
    int grr = row0 + wm * 32 + rr;
    if (grr < M)
      *(uint4*)&hb[(size_t)grr * CDIM + hd * 64 + cc * 8] = v;
  }
}

// ---------------- fused per-row softmax+aggregate (wave per row) ----------
// Depth-4 software pipeline with statically-named slots: up to 4 hb gathers
// in flight; col indices fetched once per 64-edge chunk + shfl broadcast.
__global__ __launch_bounds__(256) void row_aggregate(const int* __restrict__ rowptr,
                                                     const int* __restrict__ colsorted,
                                                     const float* __restrict__ hl,
                                                     const float* __restrict__ hr,
                                                     const unsigned short* __restrict__ hb,
                                                     float* __restrict__ out) {
  int row = (int)((blockIdx.x * 256 + threadIdx.x) >> 6);
  int lane = threadIdx.x & 63;
  if (row >= NN) return;
  int s = rowptr[row], e = rowptr[row + 1];
  int d = e - s;
  int head = lane >> 4;
  int f8 = lane * 4;
  float hlv = hl[(size_t)row * 4 + head];
  float4 acc = make_float4(0.f, 0.f, 0.f, 0.f);
  float den = 0.f;

#define LDSLOT(S, J)                                                        \
  {                                                                         \
    int cc_ = __shfl(myc, min((J), n - 1));                                 \
    u##S = *(const ushort4*)&hb[(size_t)cc_ * CDIM + f8];                   \
    r##S = hr[(size_t)cc_ * 4 + head];                                      \
  }
#define STEP(S)                                                             \
  {                                                                         \
    float sc_ = hlv + r##S;                                                 \
    sc_ = sc_ > 0.f ? sc_ : ALPHA * sc_;                                    \
    float ee_ = __expf(sc_);                                                \
    den += ee_;                                                             \
    float4 hv_ = bf4_to_f4(u##S);                                           \
    acc.x += ee_ * hv_.x; acc.y += ee_ * hv_.y;                             \
    acc.z += ee_ * hv_.z; acc.w += ee_ * hv_.w;                             \
  }

  for (int b = 0; b < d; b += 64) {
    int n = min(64, d - b);
    int myc = colsorted[s + b + min(lane, n - 1)];
    ushort4 u0, u1, u2, u3;
    float r0, r1, r2, r3;
    LDSLOT(0, 0) LDSLOT(1, 1) LDSLOT(2, 2) LDSLOT(3, 3)
    for (int j = 0; j < n; j += 4) {
      STEP(0)
      LDSLOT(0, j + 4)
      if (j + 1 < n) STEP(1)
      LDSLOT(1, j + 5)
      if (j + 2 < n) STEP(2)
      LDSLOT(2, j + 6)
      if (j + 3 < n) STEP(3)
      LDSLOT(3, j + 7)
    }
  }
#undef LDSLOT
#undef STEP

  float rd = den > 0.f ? 1.f / den : 0.f;
  acc.x *= rd; acc.y *= rd; acc.z *= rd; acc.w *= rd;
  *(float4*)&out[(size_t)row * CDIM + f8] = acc;
}

// ---------------- launch ----------------

extern "C" void kernel_launch(void* const* d_in, const int* in_sizes, int n_in,
                              void* d_out, int out_size, void* d_ws, size_t ws_size,
                              hipStream_t stream) {
  const float* x   = (const float*)d_in[0];
  const int*  edge = (const int*)d_in[1];
  const float* W   = (const float*)d_in[2];
  const float* al  = (const float*)d_in[3];
  const float* ar  = (const float*)d_in[4];
  float* out = (float*)d_out;

  char* base = (char*)d_ws;
  unsigned short* hb = (unsigned short*)base;                    // NN*256 bf16 = 25.6MB
  float* hl = (float*)(base + (size_t)NN * CDIM * 2);            // NN*4
  float* hr = hl + (size_t)NN * NHEAD;                           // NN*4
  unsigned short* wt_hi = (unsigned short*)(hr + (size_t)NN * NHEAD);  // 65536
  unsigned short* wt_lo = wt_hi + KDIM * CDIM;                   // 65536
  int* deg       = (int*)(wt_lo + KDIM * CDIM);                  // NN (scan then consumed)
  int* rowptr    = deg + NN;                                     // NN+1
  int* colsorted = rowptr + NN + 1;                              // NE

  hipMemsetAsync(deg, 0, (size_t)NN * sizeof(int), stream);

  deg_count_wcvt<<<(NE + 255) / 256, 256, 0, stream>>>(edge, deg, W, wt_hi, wt_lo);
  scan_all<<<1, 1024, 0, stream>>>(deg, rowptr);
  scatter_edges<<<(NE + 255) / 256, 256, 0, stream>>>(edge, rowptr, deg, colsorted);

  gemm_fused<<<dim3(2, (NN + 63) / 64), 256, 0, stream>>>(x, wt_hi, wt_lo, al, ar, hb, hl, hr, NN);

  row_aggregate<<<(NN * 64 + 255) / 256, 256, 0, stream>>>(rowptr, colsorted, hl, hr, hb, out);
}